// Round 12
// baseline (486.517 us; speedup 1.0000x reference)
//
#include <hip/hip_runtime.h>

#define NN 4096
#define NSTEPS 100
#define TPB 512
#define NBLK 256     // 1 block per CU; 16 rows per block, K pinned in VGPRs

typedef unsigned u32x4 __attribute__((ext_vector_type(4)));

// Coherent (cross-XCD) ops: sc-flagged global ops bypass the non-coherent
// L1/L2 and hit the coherence point directly.
__device__ __forceinline__ void zstore_u64(float2* p, unsigned long long u) {
    __hip_atomic_store((unsigned long long*)p, u, __ATOMIC_RELAXED,
                       __HIP_MEMORY_SCOPE_AGENT);
}
// 16B coherent poll load (2 elements per transaction). Each 8B element is
// fully covered by the one 16B read and publishes are single 8B stores, so
// per-element atomicity is preserved (no intra-element tearing possible).
#define ZLOAD16(dst, addr)                                          \
    asm volatile("global_load_dwordx4 %0, %1, off sc0 sc1"          \
                 : "=v"(dst) : "v"(addr) : "memory")

// R12 = R5 with CONTIGUOUS column ownership, deconfounding R11:
//  R11 halved poll transactions via a PERMUTED buffer, but that scattered
//  the publish (WRITE_SIZE 6.4->12.7MB, 2->16 lines/block) and made each
//  16B granule span two distant producers -> net regression. The permute was
//  never needed: reassigning thread (w,lane) to the 8 CONTIGUOUS original
//  columns w*512 + lane*8 + {0..7} keeps the wave's column range (and thus
//  the dot/butterfly/P/ODE math) IDENTICAL to R5 while making the poll 4 x
//  16B sc loads of the PLAIN buffer. Publish stays R5-contiguous. Each
//  granule's two elements come from the same producer block (even/odd pairs
//  never straddle a 16-row boundary).
//  - Poll transactions: 1M -> 512K per round, with zero store-side change.
//  - kA loads stay coalesced: each lane reads 32 contiguous B/row (2xfloat4);
//    a wave covers 2KB/row contiguously.
//  - Issue points identical to R5: round A issued right after the dot
//    (hidden under butterfly+barrier+ODE), checked at next loop top.
//  - vmcnt(1) at first check (the 1 = this wave's publish store, issued
//    after the 4 poll loads; vmcnt retires in issue order, wave-level),
//    vmcnt(0) in retries, each + sched_barrier(0) (rule #18). Proven in R11.
//  - kA: 128 f32, per-iteration "+v" pin (R7/R8/R9 proved alternatives worse).
__global__ __launch_bounds__(TPB, 2) void k_persist(
    const float* __restrict__ K, const float2* __restrict__ z0,
    float2* __restrict__ zb0, float2* __restrict__ zb1,
    float2* __restrict__ zfinal, const float* __restrict__ omega_p,
    const float* __restrict__ dt_p) {
    __shared__ float P[2][8][68];   // 68: +4 pad so q-stride hits new banks

    const int tid  = threadIdx.x;
    const int bid  = blockIdx.x;
    const int w    = tid >> 6, lane = tid & 63;   // w = column-eighth
    const int cb   = w * 512 + lane * 8;          // 8 CONTIGUOUS cols per thread

    const float omega = *omega_p;
    const float dt    = *dt_p;
    const float inv2n = 1.0f / (2.0f * NN);

    // ---- K fragment: 16 rows x 8 contiguous cols = 128 scalars ----
    float kA[16][8];
#pragma unroll
    for (int r = 0; r < 16; ++r) {
        const float4* Kr4 = (const float4*)(K + (size_t)(bid * 16 + r) * NN + cb);
        float4 k0 = Kr4[0], k1 = Kr4[1];
        kA[r][0] = k0.x; kA[r][1] = k0.y; kA[r][2] = k0.z; kA[r][3] = k0.w;
        kA[r][4] = k1.x; kA[r][5] = k1.y; kA[r][6] = k1.z; kA[r][7] = k1.w;
    }

    // ---- persistent ODE state: wave w's lanes 0/32 hold rows 2w, 2w+1 ----
    float x = 0.f, y = 0.f;
    if ((lane & 31) == 0) {
        float2 zc = z0[bid * 16 + 2 * w + (lane >> 5)];
        x = zc.x; y = zc.y;
    }

    u32x4 va[4];   // in-flight tagged 16B loads for the NEXT step

    for (int s = 0; s < NSTEPS; ++s) {
        // Pin kA in registers: opaque redefinition each iteration so the
        // compiler can neither spill-and-reload nor refold the global loads.
#pragma unroll
        for (int r = 0; r < 16; ++r)
#pragma unroll
            for (int j = 0; j < 8; ++j) asm volatile("" : "+v"(kA[r][j]));

        // ---- gather this thread's 8 z elements into registers ----
        float zre[8], zim[8];
        if (s == 0) {
            const float2* zz = z0 + cb;          // 64B contiguous
#pragma unroll
            for (int j = 0; j < 8; ++j) {
                float2 zc = zz[j];
                zre[j] = zc.x; zim[j] = zc.y;
            }
        } else {
            // va[] was issued after last step's dot (round A, hidden under
            // butterfly+barrier+ODE). Check; re-poll stale granules batched.
            const float2* zsrc = (s & 1) ? zb1 : zb0;
            const unsigned tag = (unsigned)(s & 7);
            const float2* gb = zsrc + cb;
            // wait the 4 loads; leave the (later-issued) publish store in flight
            asm volatile("s_waitcnt vmcnt(1)" ::: "memory");
            __builtin_amdgcn_sched_barrier(0);
            unsigned stale = 0u;
#pragma unroll
            for (int g = 0; g < 4; ++g)
                if (((va[g][0] & 7u) != tag) || ((va[g][2] & 7u) != tag))
                    stale |= 1u << g;
            while (stale) {
                __builtin_amdgcn_s_sleep(1);
#pragma unroll
                for (int g = 0; g < 4; ++g)
                    if (stale & (1u << g)) ZLOAD16(va[g], gb + 2 * g);
                asm volatile("s_waitcnt vmcnt(0)" ::: "memory");
                __builtin_amdgcn_sched_barrier(0);
#pragma unroll
                for (int g = 0; g < 4; ++g)
                    if ((stale & (1u << g)) && ((va[g][0] & 7u) == tag) &&
                        ((va[g][2] & 7u) == tag))
                        stale &= ~(1u << g);
            }
#pragma unroll
            for (int g = 0; g < 4; ++g) {
                union { unsigned u; float f; } t0, t1, t2, t3;
                t0.u = va[g][0]; t1.u = va[g][1];
                t2.u = va[g][2]; t3.u = va[g][3];
                zre[2 * g]     = t0.f; zim[2 * g]     = t1.f;
                zre[2 * g + 1] = t2.f; zim[2 * g + 1] = t3.f;
            }
        }

        // ---- dots: 16 rows x 8 cols per thread, K and z in registers ----
        float sr[16], si[16];
#pragma unroll
        for (int r = 0; r < 16; ++r) { sr[r] = 0.f; si[r] = 0.f; }
#pragma unroll
        for (int j = 0; j < 8; ++j) {
#pragma unroll
            for (int r = 0; r < 16; ++r) {
                sr[r] += kA[r][j] * zre[j];
                si[r] += kA[r][j] * zim[j];
            }
        }

        // ---- EARLY-ISSUE round A for step s+1 (R5 placement: flies during
        //      butterfly + barrier + ODE; checked at next loop top) ----
        if (s + 1 < NSTEPS) {
            const float2* zn = ((s + 1) & 1) ? zb1 : zb0;
            const float2* gb = zn + cb;
#pragma unroll
            for (int g = 0; g < 4; ++g) ZLOAD16(va[g], gb + 2 * g);
        }

        // ---- distribute-and-halve butterfly: 31 shuffles/thread ----
        // acc index i: i<16 -> Re(row i); i>=16 -> Im(row i-16).
        float a32[32];
#pragma unroll
        for (int r = 0; r < 16; ++r) { a32[r] = sr[r]; a32[16 + r] = si[r]; }
        float b16[16];
#pragma unroll
        for (int m = 0; m < 16; ++m) {
            float aa = a32[2 * m], bb = a32[2 * m + 1];
            bool hi = lane & 1;
            float snd = hi ? aa : bb, kp = hi ? bb : aa;
            b16[m] = kp + __shfl_xor(snd, 1, 64);
        }
        float b8[8];
#pragma unroll
        for (int m = 0; m < 8; ++m) {
            float aa = b16[2 * m], bb = b16[2 * m + 1];
            bool hi = lane & 2;
            float snd = hi ? aa : bb, kp = hi ? bb : aa;
            b8[m] = kp + __shfl_xor(snd, 2, 64);
        }
        float b4[4];
#pragma unroll
        for (int m = 0; m < 4; ++m) {
            float aa = b8[2 * m], bb = b8[2 * m + 1];
            bool hi = lane & 4;
            float snd = hi ? aa : bb, kp = hi ? bb : aa;
            b4[m] = kp + __shfl_xor(snd, 4, 64);
        }
        float b2[2];
#pragma unroll
        for (int m = 0; m < 2; ++m) {
            float aa = b4[2 * m], bb = b4[2 * m + 1];
            bool hi = lane & 8;
            float snd = hi ? aa : bb, kp = hi ? bb : aa;
            b2[m] = kp + __shfl_xor(snd, 8, 64);
        }
        {
            float aa = b2[0], bb = b2[1];
            bool hi = lane & 16;
            float snd = hi ? aa : bb, kp = hi ? bb : aa;
            float red = kp + __shfl_xor(snd, 16, 64);
            // lane l holds acc index (l&31), summed over its 32-lane half
            P[s & 1][w][lane] = red;
        }
        __syncthreads();

        // ---- per-wave ODE: wave w owns rows 2w, 2w+1 ----
        {
            const int par = s & 1;
            const int r0 = 2 * w, r1 = 2 * w + 1;
            int q    = lane & 7;
            int half = (lane >> 3) & 1;
            int sel  = lane >> 4;                       // 0..3
            int rr   = (sel & 2) ? r1 : r0;
            int idx  = ((sel & 1) << 4) + rr;           // +16 selects Im
            float val = P[par][q][half * 32 + idx];
            val += __shfl_xor(val, 1, 64);              // sum over q
            val += __shfl_xor(val, 2, 64);
            val += __shfl_xor(val, 4, 64);
            val += __shfl_xor(val, 8, 64);              // sum the two halves
            float other = __shfl_xor(val, 16, 64);      // Im to lanes 0/32
            if ((lane & 31) == 0) {                     // lanes 0 and 32
                float u  = val;                         // Re(K z) row
                float vv = other;                       // Im(K z) row
                float A = x * x - y * y;                // Re(z^2)
                float B = 2.0f * x * y;                 // Im(z^2)
                float dzr = inv2n * (u  - (u * A + vv * B)) + omega * x;
                float dzi = inv2n * (vv - (u * B - vv * A)) + omega * y;
                float nx = x + dt * dzr;
                float ny = y + dt * dzi;
                float a2 = nx * nx + ny * ny;
                if (a2 >= 0.999f * 0.999f) {
                    float sc = 0.999f / sqrtf(a2);
                    nx *= sc; ny *= sc;
                }
                x = nx; y = ny;                         // state stays in regs
                int gr = bid * 16 + r0 + (lane >> 5);
                if (s == NSTEPS - 1) {
                    zfinal[gr] = make_float2(nx, ny);   // plain, untagged
                } else {
                    union { float f; unsigned u; } cx, cy;
                    cx.f = nx; cy.f = ny;
                    cx.u = (cx.u & ~7u) | (unsigned)((s + 1) & 7);
                    unsigned long long pk =
                        (unsigned long long)cx.u |
                        ((unsigned long long)cy.u << 32);
                    float2* zo = ((s + 1) & 1) ? zb1 : zb0;
                    zstore_u64(zo + gr, pk);            // R5 publish: contiguous
                }
            }
        }
        // no trailing barrier — P is parity-double-buffered and the tag
        // protocol transitively orders (s+2)-writes after (s)-reads
    }
}

// ---- generic fallback: per-step launches ----
__global__ __launch_bounds__(256) void k_step_f32(
    const float* __restrict__ K, const float2* __restrict__ zin,
    float2* __restrict__ zout, const float* __restrict__ omega_p,
    const float* __restrict__ dt_p, int n) {
    const int wave = threadIdx.x >> 6;
    const int lane = threadIdx.x & 63;
    const int row  = blockIdx.x * 4 + wave;
    if (row >= n) return;
    float sr = 0.0f, si = 0.0f;
    for (int c = lane; c < n; c += 64) {
        float k = K[(size_t)row * n + c];
        float2 z = zin[c];
        sr += k * z.x;
        si += k * z.y;
    }
#pragma unroll
    for (int off = 32; off; off >>= 1) {
        sr += __shfl_down(sr, off, 64);
        si += __shfl_down(si, off, 64);
    }
    if (lane == 0) {
        float u = sr, v = si;
        float2 zc = zin[row];
        float x = zc.x, y = zc.y;
        float inv2n = 1.0f / (2.0f * n);
        float A = x * x - y * y, B = 2.0f * x * y;
        float dzr = inv2n * (u - (u * A + v * B)) + (*omega_p) * x;
        float dzi = inv2n * (v - (u * B - v * A)) + (*omega_p) * y;
        float nx = x + (*dt_p) * dzr, ny = y + (*dt_p) * dzi;
        float a2 = nx * nx + ny * ny;
        if (a2 >= 0.999f * 0.999f) { float sc = 0.999f / sqrtf(a2); nx *= sc; ny *= sc; }
        zout[row] = make_float2(nx, ny);
    }
}

extern "C" void kernel_launch(void* const* d_in, const int* in_sizes, int n_in,
                              void* d_out, int out_size, void* d_ws, size_t ws_size,
                              hipStream_t stream) {
    const float2* z0      = (const float2*)d_in[0];
    const float*  K       = (const float*)d_in[1];
    const float*  omega_p = (const float*)d_in[2];
    const float*  dt_p    = (const float*)d_in[3];
    const int n = in_sizes[0] / 2;
    float2* out = (float2*)d_out;

    const size_t need = 2 * (size_t)NN * sizeof(float2);   // two z buffers
    if (n == NN && ws_size >= need) {
        float2* zb0 = (float2*)d_ws;
        float2* zb1 = zb0 + NN;
        (void)hipMemsetAsync(d_ws, 0, need, stream);  // tag 0 != live tags 1,2
        k_persist<<<NBLK, TPB, 0, stream>>>(K, z0, zb0, zb1, out,
                                            omega_p, dt_p);
    } else {
        float2* zb0 = (float2*)d_ws;
        float2* zb1 = zb0 + n;
        const float2* cur = z0;
        for (int s = 0; s < NSTEPS; ++s) {
            float2* nxt = (s == NSTEPS - 1) ? out : ((s & 1) ? zb1 : zb0);
            k_step_f32<<<(n + 3) / 4, 256, 0, stream>>>(K, cur, nxt, omega_p, dt_p, n);
            cur = nxt;
        }
    }
}